// Round 13
// baseline (67.992 us; speedup 1.0000x reference)
//
#include <hip/hip_runtime.h>
#include <math.h>

#define N_NODES 768
#define N_EDGES 12288
#define D_INF 6
#define H 256
#define CAP 128
#define LC 256

// ============ K1 k_prep (heterogeneous) ============
// blocks [0,256):   LDS histogram + compact -> cnt/slots + h1 (3 nodes/block)
// blocks [256,320): Wcombo = Wc2 @ [We1a|We1b] (256x512) + bias_c row
__global__ __launch_bounds__(256) void k_prep(
    const float* __restrict__ x, const int* __restrict__ ei,
    const float* __restrict__ Wc1, const float* __restrict__ bc1,
    const float* __restrict__ Wc2, const float* __restrict__ bc2,
    const float* __restrict__ We1, const float* __restrict__ be1,
    int* __restrict__ cnt_g, int* __restrict__ slots, float* __restrict__ h1,
    float* __restrict__ Wcombo, float* __restrict__ bias_c) {
    const int t = threadIdx.x;
    if (blockIdx.x < 256) {
        __shared__ int s_cnt[N_NODES];
        __shared__ int s_list[LC];
        __shared__ int s_nm, s_pos[3];
        __shared__ float s_agg[3][D_INF];
        const int b = blockIdx.x, v0 = b * 3;
        const int* src = ei;
        const int* dst = ei + N_EDGES;

        for (int v = t; v < N_NODES; v += 256) s_cnt[v] = 0;
        if (t == 0) s_nm = 0;
        if (t < 3) s_pos[t] = 0;
        if (t < 3 * D_INF) ((float*)s_agg)[t] = 0.f;
        __syncthreads();
        for (int e = t; e < N_EDGES; e += 256) {
            int d = dst[e];
            atomicAdd(&s_cnt[d], 1);
            unsigned li = (unsigned)(d - v0);
            if (li < 3u) {
                int p = atomicAdd(&s_nm, 1);
                if (p < LC) s_list[p] = (src[e] << 2) | (int)li;
            }
        }
        __syncthreads();
        const int nm = min(s_nm, LC);
        if (t < 3) cnt_g[v0 + t] = s_cnt[v0 + t];
        for (int m = t; m < nm; m += 256) {
            int pk = s_list[m];
            int s = pk >> 2, li = pk & 3;
            int p = atomicAdd(&s_pos[li], 1);
            if (p < CAP) slots[(v0 + li) * CAP + p] = s;
            float w = rsqrtf((float)(s_cnt[s] + 1)) * rsqrtf((float)(s_cnt[v0 + li] + 1));
            #pragma unroll
            for (int k = 0; k < D_INF; ++k)
                atomicAdd(&s_agg[li][k], w * x[s * D_INF + k]);
        }
        if (t < 3) {   // self-loops
            int v = v0 + t;
            float dv2 = 1.0f / (float)(s_cnt[v] + 1);
            #pragma unroll
            for (int k = 0; k < D_INF; ++k)
                atomicAdd(&s_agg[t][k], dv2 * x[v * D_INF + k]);
        }
        __syncthreads();
        #pragma unroll
        for (int r = 0; r < 3; ++r) {
            float acc = bc1[t];
            #pragma unroll
            for (int k = 0; k < D_INF; ++k)
                acc = fmaf(s_agg[r][k], Wc1[k * H + t], acc);
            h1[(v0 + r) * H + t] = (acc > 0.f) ? acc : expm1f(acc);
        }
    } else {
        // ---- Wcombo tile: (kt,ot) in 8x8; block = 32 k-rows x 64 o-cols ----
        const int ib = blockIdx.x - 256;
        const int kt = ib >> 3, ot = ib & 7;
        const int k0c = kt * 32, o0 = ot * 64;
        const int oc4 = (t & 15) * 4, rg2 = t >> 4;   // 16 col-quads x 16 row-pairs
        const float* wbase = (o0 < H) ? (We1 + o0 + oc4)
                                      : (We1 + (size_t)H * H + (o0 - H) + oc4);
        const int r0 = k0c + rg2 * 2;
        float4 a0 = {0.f, 0.f, 0.f, 0.f}, a1 = a0;
        for (int c = 0; c < H; ++c) {
            float4 wv = *(const float4*)(wbase + (size_t)c * H);
            float w0 = Wc2[(size_t)c * 0 + (size_t)(r0 + 0) * H + c];
            float w1 = Wc2[(size_t)(r0 + 1) * H + c];
            a0.x = fmaf(w0, wv.x, a0.x); a0.y = fmaf(w0, wv.y, a0.y);
            a0.z = fmaf(w0, wv.z, a0.z); a0.w = fmaf(w0, wv.w, a0.w);
            a1.x = fmaf(w1, wv.x, a1.x); a1.y = fmaf(w1, wv.y, a1.y);
            a1.z = fmaf(w1, wv.z, a1.z); a1.w = fmaf(w1, wv.w, a1.w);
        }
        *(float4*)(Wcombo + (size_t)(r0 + 0) * 512 + o0 + oc4) = a0;
        *(float4*)(Wcombo + (size_t)(r0 + 1) * 512 + o0 + oc4) = a1;
        if (kt == 0 && t < 16) {   // bias_c = bc2 @ We1cat (+ be1 on j-half)
            const float* wb2 = (o0 < H) ? (We1 + o0 + t * 4)
                                        : (We1 + (size_t)H * H + (o0 - H) + t * 4);
            float4 bs;
            if (o0 >= H) {
                bs.x = be1[o0 - H + t * 4 + 0]; bs.y = be1[o0 - H + t * 4 + 1];
                bs.z = be1[o0 - H + t * 4 + 2]; bs.w = be1[o0 - H + t * 4 + 3];
            } else bs = make_float4(0.f, 0.f, 0.f, 0.f);
            for (int c = 0; c < H; ++c) {
                float4 wv = *(const float4*)(wb2 + (size_t)c * H);
                float bv = bc2[c];
                bs.x = fmaf(bv, wv.x, bs.x); bs.y = fmaf(bv, wv.y, bs.y);
                bs.z = fmaf(bv, wv.z, bs.z); bs.w = fmaf(bv, wv.w, bs.w);
            }
            *(float4*)(bias_c + o0 + t * 4) = bs;
        }
    }
}

// ============ K2 k_mid: agg(h1) -> [ai|ajT] = agg @ Wcombo + bias_c ============
// 1024 thr, 3 nodes/block. Single GEMM phase (Wcombo), 16-wave k-split with
// block-staggered k-start to dehotspot L2 broadcast reads.
__global__ __launch_bounds__(1024) void k_mid(
    const float* __restrict__ h1, const int* __restrict__ cnt,
    const int* __restrict__ slots, const float* __restrict__ Wcombo,
    const float* __restrict__ bias_c, float* __restrict__ aib,
    float* __restrict__ ajcT) {
    __shared__ int   s_s[3][CAP];
    __shared__ float s_w[3][CAP];
    __shared__ int   s_cc[3];
    __shared__ float s_dv[3];
    __shared__ __align__(16) float s_agg[3][H];
    __shared__ __align__(16) float s_part[16][6][H];   // 98.3 KB
    const int t = threadIdx.x, b = blockIdx.x;
    const int q = t >> 8, tc = t & 255;
    const int lane = t & 63, w = t >> 6;
    const int v0 = b * 3;
    const int k0 = ((w + b) & 15) * 16;   // staggered

    // ---- P0: (s,w) preload ----
    if (t < 3) {
        int c = cnt[v0 + t];
        s_cc[t] = min(c, CAP);
        s_dv[t] = rsqrtf((float)(c + 1));
    }
    __syncthreads();
    if (q < 3) {
        int ccq = s_cc[q];
        for (int i = tc; i < ccq; i += 256) {
            int s = slots[(v0 + q) * CAP + i];
            s_s[q][i] = s;
            s_w[q][i] = rsqrtf((float)(cnt[s] + 1)) * s_dv[q];
        }
    }
    __syncthreads();

    // ---- P1: agg = (A h1) rows ----
    if (q < 3) {
        float dv = s_dv[q];
        float acc = dv * dv * h1[(size_t)(v0 + q) * H + tc];
        int ccq = s_cc[q];
        #pragma unroll 4
        for (int n = 0; n < ccq; ++n)
            acc = fmaf(s_w[q][n], h1[(size_t)s_s[q][n] * H + tc], acc);
        s_agg[q][tc] = acc;
    }
    __syncthreads();

    // ---- P2: [ai | ajT] = agg @ Wcombo ----
    {
        float a[3][16];
        #pragma unroll
        for (int r = 0; r < 3; ++r)
            #pragma unroll
            for (int qq = 0; qq < 4; ++qq) {
                float4 v = *(const float4*)&s_agg[r][k0 + qq * 4];
                a[r][qq * 4 + 0] = v.x; a[r][qq * 4 + 1] = v.y;
                a[r][qq * 4 + 2] = v.z; a[r][qq * 4 + 3] = v.w;
            }
        float4 ca0 = {0.f, 0.f, 0.f, 0.f}, ca1 = ca0, ca2 = ca0;
        float4 cb0 = ca0, cb1 = ca0, cb2 = ca0;
        #pragma unroll
        for (int kk = 0; kk < 16; ++kk) {
            int k = k0 + kk;
            float4 wa = *(const float4*)(Wcombo + (size_t)k * 512 + (lane << 2));
            float4 wb = *(const float4*)(Wcombo + (size_t)k * 512 + 256 + (lane << 2));
            ca0.x = fmaf(a[0][kk], wa.x, ca0.x); ca0.y = fmaf(a[0][kk], wa.y, ca0.y);
            ca0.z = fmaf(a[0][kk], wa.z, ca0.z); ca0.w = fmaf(a[0][kk], wa.w, ca0.w);
            ca1.x = fmaf(a[1][kk], wa.x, ca1.x); ca1.y = fmaf(a[1][kk], wa.y, ca1.y);
            ca1.z = fmaf(a[1][kk], wa.z, ca1.z); ca1.w = fmaf(a[1][kk], wa.w, ca1.w);
            ca2.x = fmaf(a[2][kk], wa.x, ca2.x); ca2.y = fmaf(a[2][kk], wa.y, ca2.y);
            ca2.z = fmaf(a[2][kk], wa.z, ca2.z); ca2.w = fmaf(a[2][kk], wa.w, ca2.w);
            cb0.x = fmaf(a[0][kk], wb.x, cb0.x); cb0.y = fmaf(a[0][kk], wb.y, cb0.y);
            cb0.z = fmaf(a[0][kk], wb.z, cb0.z); cb0.w = fmaf(a[0][kk], wb.w, cb0.w);
            cb1.x = fmaf(a[1][kk], wb.x, cb1.x); cb1.y = fmaf(a[1][kk], wb.y, cb1.y);
            cb1.z = fmaf(a[1][kk], wb.z, cb1.z); cb1.w = fmaf(a[1][kk], wb.w, cb1.w);
            cb2.x = fmaf(a[2][kk], wb.x, cb2.x); cb2.y = fmaf(a[2][kk], wb.y, cb2.y);
            cb2.z = fmaf(a[2][kk], wb.z, cb2.z); cb2.w = fmaf(a[2][kk], wb.w, cb2.w);
        }
        *(float4*)&s_part[w][0][lane << 2] = ca0;
        *(float4*)&s_part[w][1][lane << 2] = ca1;
        *(float4*)&s_part[w][2][lane << 2] = ca2;
        *(float4*)&s_part[w][3][lane << 2] = cb0;
        *(float4*)&s_part[w][4][lane << 2] = cb1;
        *(float4*)&s_part[w][5][lane << 2] = cb2;
    }
    __syncthreads();
    for (int idx = t; idx < 6 * H; idx += 1024) {
        int r6 = idx >> 8, c = idx & 255;
        float v = 0.f;
        #pragma unroll
        for (int ww = 0; ww < 16; ++ww) v += s_part[ww][r6][c];
        if (r6 < 3) aib[(size_t)(v0 + r6) * H + c] = v + bias_c[c];
        else        ajcT[(size_t)c * N_NODES + v0 + (r6 - 3)] = v + bias_c[H + c];
    }
}

// ============ K3 k_pair2: logits + fused row softmax ============
// 512 thr = 8 waves x 32-h slices, block-staggered; j as 3 x float4 chunks.
__global__ __launch_bounds__(512) void k_pair2(
    const float* __restrict__ aib, const float* __restrict__ ajcT,
    const float* __restrict__ We2, float* __restrict__ out) {
    __shared__ float s_ai[3 * H];
    __shared__ float s_w2[H];
    __shared__ __align__(16) float s_p[8 * 3 * N_NODES];   // 73.7 KB
    __shared__ float s_lg[3 * N_NODES];
    __shared__ float red[3 * 256];
    const int t = threadIdx.x, b = blockIdx.x;
    const int lane = t & 63, w = t >> 6;
    const int i0 = b * 3;
    const int h0 = ((w + b) & 7) * 32;   // staggered

    for (int i = t; i < 3 * H; i += 512)
        s_ai[i] = aib[(size_t)(i0 + (i >> 8)) * H + (i & 255)];
    if (t < H) s_w2[t] = We2[t];
    __syncthreads();

    float4 acc[3][3];
    #pragma unroll
    for (int r = 0; r < 3; ++r)
        #pragma unroll
        for (int jj = 0; jj < 3; ++jj)
            acc[r][jj] = make_float4(0.f, 0.f, 0.f, 0.f);

    #pragma unroll 4
    for (int hh = 0; hh < 32; ++hh) {
        int h = h0 + hh;
        float wv = s_w2[h];
        float a0 = s_ai[h], a1 = s_ai[H + h], a2 = s_ai[2 * H + h];
        const float* col = ajcT + (size_t)h * N_NODES + (lane << 2);
        #pragma unroll
        for (int jj = 0; jj < 3; ++jj) {
            float4 bv = *(const float4*)(col + jj * 256);
            acc[0][jj].x = fmaf(fmaxf(a0 + bv.x, 0.f), wv, acc[0][jj].x);
            acc[0][jj].y = fmaf(fmaxf(a0 + bv.y, 0.f), wv, acc[0][jj].y);
            acc[0][jj].z = fmaf(fmaxf(a0 + bv.z, 0.f), wv, acc[0][jj].z);
            acc[0][jj].w = fmaf(fmaxf(a0 + bv.w, 0.f), wv, acc[0][jj].w);
            acc[1][jj].x = fmaf(fmaxf(a1 + bv.x, 0.f), wv, acc[1][jj].x);
            acc[1][jj].y = fmaf(fmaxf(a1 + bv.y, 0.f), wv, acc[1][jj].y);
            acc[1][jj].z = fmaf(fmaxf(a1 + bv.z, 0.f), wv, acc[1][jj].z);
            acc[1][jj].w = fmaf(fmaxf(a1 + bv.w, 0.f), wv, acc[1][jj].w);
            acc[2][jj].x = fmaf(fmaxf(a2 + bv.x, 0.f), wv, acc[2][jj].x);
            acc[2][jj].y = fmaf(fmaxf(a2 + bv.y, 0.f), wv, acc[2][jj].y);
            acc[2][jj].z = fmaf(fmaxf(a2 + bv.z, 0.f), wv, acc[2][jj].z);
            acc[2][jj].w = fmaf(fmaxf(a2 + bv.w, 0.f), wv, acc[2][jj].w);
        }
    }
    #pragma unroll
    for (int r = 0; r < 3; ++r)
        #pragma unroll
        for (int jj = 0; jj < 3; ++jj)
            *(float4*)&s_p[(w * 3 + r) * N_NODES + jj * 256 + (lane << 2)] = acc[r][jj];
    __syncthreads();

    for (int idx = t; idx < 3 * N_NODES; idx += 512) {
        int r = idx / N_NODES, j = idx - r * N_NODES;
        float v = 0.f;
        #pragma unroll
        for (int ww = 0; ww < 8; ++ww) v += s_p[(ww * 3 + r) * N_NODES + j];
        s_lg[idx] = (j == i0 + r) ? -INFINITY : v;
    }
    __syncthreads();

    const int tc = t & 255, th = t >> 8;
    if (th == 0) {
        red[tc] = fmaxf(fmaxf(s_lg[tc], s_lg[tc + 256]), s_lg[tc + 512]);
        red[512 + tc] = fmaxf(fmaxf(s_lg[1536 + tc], s_lg[1536 + tc + 256]),
                              s_lg[1536 + tc + 512]);
    } else {
        red[256 + tc] = fmaxf(fmaxf(s_lg[768 + tc], s_lg[768 + tc + 256]),
                              s_lg[768 + tc + 512]);
    }
    __syncthreads();
    for (int s = 128; s > 0; s >>= 1) {
        if (th == 0 && tc < s) {
            red[tc] = fmaxf(red[tc], red[tc + s]);
            red[512 + tc] = fmaxf(red[512 + tc], red[512 + tc + s]);
        } else if (th == 1 && tc < s) {
            red[256 + tc] = fmaxf(red[256 + tc], red[256 + tc + s]);
        }
        __syncthreads();
    }
    float mx0 = red[0], mx1 = red[256], mx2 = red[512];
    __syncthreads();
    if (th == 0) {
        red[tc] = __expf(s_lg[tc] - mx0) + __expf(s_lg[tc + 256] - mx0)
                + __expf(s_lg[tc + 512] - mx0);
        red[512 + tc] = __expf(s_lg[1536 + tc] - mx2) + __expf(s_lg[1536 + tc + 256] - mx2)
                      + __expf(s_lg[1536 + tc + 512] - mx2);
    } else {
        red[256 + tc] = __expf(s_lg[768 + tc] - mx1) + __expf(s_lg[768 + tc + 256] - mx1)
                      + __expf(s_lg[768 + tc + 512] - mx1);
    }
    __syncthreads();
    for (int s = 128; s > 0; s >>= 1) {
        if (th == 0 && tc < s) {
            red[tc] += red[tc + s];
            red[512 + tc] += red[512 + tc + s];
        } else if (th == 1 && tc < s) {
            red[256 + tc] += red[256 + tc + s];
        }
        __syncthreads();
    }
    float iv0 = 1.0f / red[0], iv1 = 1.0f / red[256], iv2 = 1.0f / red[512];

    for (int idx = t; idx < 3 * N_NODES; idx += 512) {
        int r = idx / N_NODES, j = idx - r * N_NODES;
        float m = (r == 0) ? mx0 : (r == 1) ? mx1 : mx2;
        float iv = (r == 0) ? iv0 : (r == 1) ? iv1 : iv2;
        out[(size_t)(i0 + r) * N_NODES + j] = __expf(s_lg[idx] - m) * iv;
    }
}

extern "C" void kernel_launch(void* const* d_in, const int* in_sizes, int n_in,
                              void* d_out, int out_size, void* d_ws, size_t ws_size,
                              hipStream_t stream) {
    const float* x   = (const float*)d_in[0];
    const int*   ei  = (const int*)d_in[1];
    const float* Wc1 = (const float*)d_in[2];
    const float* bc1 = (const float*)d_in[3];
    const float* Wc2 = (const float*)d_in[4];
    const float* bc2 = (const float*)d_in[5];
    const float* We1 = (const float*)d_in[6];
    const float* be1 = (const float*)d_in[7];
    const float* We2 = (const float*)d_in[8];
    // be2 (d_in[9]) unused: softmax shift-invariant (TEMPERATURE=1 likewise).
    float* out = (float*)d_out;

    char* ws = (char*)d_ws;
    int*   cnt    = (int*)(ws + 0);            // 3072
    int*   slots  = (int*)(ws + 4096);         // 393216
    float* h1     = (float*)(ws + 397312);     // 786432
    float* aib    = (float*)(ws + 1183744);    // 786432
    float* ajcT   = (float*)(ws + 1970176);    // 786432
    float* Wcombo = (float*)(ws + 2756608);    // 524288
    float* bias_c = (float*)(ws + 3280896);    // 2048

    k_prep<<<320, 256, 0, stream>>>(x, ei, Wc1, bc1, Wc2, bc2, We1, be1,
                                    cnt, slots, h1, Wcombo, bias_c);
    k_mid<<<N_NODES / 3, 1024, 0, stream>>>(h1, cnt, slots, Wcombo, bias_c,
                                            aib, ajcT);
    k_pair2<<<N_NODES / 3, 512, 0, stream>>>(aib, ajcT, We2, out);
}

// Round 14
// 54.121 us; speedup vs baseline: 1.2563x; 1.2563x over previous
//
#include <hip/hip_runtime.h>
#include <math.h>

#define N_NODES 768
#define N_EDGES 12288
#define D_INF 6
#define H 256
#define CAP 128
#define LC 256

// ============ K1 k_prep: LDS histogram + compact -> cnt/slots + G = (A x) ============
// G (768x6, 18KB) replaces materialized h1; h1 is recomputed in k_mid from G.
__global__ __launch_bounds__(256) void k_prep(
    const float* __restrict__ x, const int* __restrict__ ei,
    int* __restrict__ cnt_g, int* __restrict__ slots, float* __restrict__ G) {
    __shared__ int s_cnt[N_NODES];
    __shared__ int s_list[LC];
    __shared__ int s_nm, s_pos[3];
    __shared__ float s_agg[3][D_INF];
    const int t = threadIdx.x, b = blockIdx.x, v0 = b * 3;
    const int* src = ei;
    const int* dst = ei + N_EDGES;

    for (int v = t; v < N_NODES; v += 256) s_cnt[v] = 0;
    if (t == 0) s_nm = 0;
    if (t < 3) s_pos[t] = 0;
    if (t < 3 * D_INF) ((float*)s_agg)[t] = 0.f;
    __syncthreads();
    for (int e = t; e < N_EDGES; e += 256) {
        int d = dst[e];
        atomicAdd(&s_cnt[d], 1);
        unsigned li = (unsigned)(d - v0);
        if (li < 3u) {
            int p = atomicAdd(&s_nm, 1);
            if (p < LC) s_list[p] = (src[e] << 2) | (int)li;
        }
    }
    __syncthreads();
    const int nm = min(s_nm, LC);
    if (t < 3) cnt_g[v0 + t] = s_cnt[v0 + t];
    for (int m = t; m < nm; m += 256) {
        int pk = s_list[m];
        int s = pk >> 2, li = pk & 3;
        int p = atomicAdd(&s_pos[li], 1);
        if (p < CAP) slots[(v0 + li) * CAP + p] = s;
        float w = rsqrtf((float)(s_cnt[s] + 1)) * rsqrtf((float)(s_cnt[v0 + li] + 1));
        #pragma unroll
        for (int k = 0; k < D_INF; ++k)
            atomicAdd(&s_agg[li][k], w * x[s * D_INF + k]);
    }
    if (t < 3) {   // self-loops
        int v = v0 + t;
        float dv2 = 1.0f / (float)(s_cnt[v] + 1);
        #pragma unroll
        for (int k = 0; k < D_INF; ++k)
            atomicAdd(&s_agg[t][k], dv2 * x[v * D_INF + k]);
    }
    __syncthreads();
    if (t < 3 * D_INF) G[v0 * D_INF + t] = ((float*)s_agg)[t];
}

// ============ K2 k_mid: h1-remat gather -> h2 -> ai/ajcT, 3 nodes/block ============
// 1024 thr. P0: stage G/Wc1/bc1 + (s,w) lists. P1: agg rows with h1 recomputed
// in-register from G (6 FMA + elu per elem; no global h1 traffic).
// P2: h2 = agg@Wc2+bc2 (16-wave k-split, A via LDS broadcast, W global b128).
// P3: [ai|ajT] = h2@We1 (+be1 on j-half).
__global__ __launch_bounds__(1024) void k_mid(
    const float* __restrict__ G, const int* __restrict__ cnt,
    const int* __restrict__ slots, const float* __restrict__ Wc1,
    const float* __restrict__ bc1, const float* __restrict__ Wc2,
    const float* __restrict__ bc2, const float* __restrict__ We1,
    const float* __restrict__ be1, float* __restrict__ aib,
    float* __restrict__ ajcT) {
    __shared__ int   s_s[3][CAP];
    __shared__ float s_w[3][CAP];
    __shared__ int   s_cc[3];
    __shared__ float s_dv[3];
    __shared__ float s_G[N_NODES * D_INF];     // 18 KB
    __shared__ float s_Wc1[D_INF * H];         // 6 KB
    __shared__ float s_bc1[H];                 // 1 KB
    __shared__ __align__(16) float s_agg[3][H];
    __shared__ __align__(16) float s_h2[3][H];
    __shared__ __align__(16) float s_part[16][6][H];   // 98.3 KB
    const int t = threadIdx.x, b = blockIdx.x;
    const int q = t >> 8, tc = t & 255;
    const int lane = t & 63, w = t >> 6;
    const int v0 = b * 3, k0 = w * 16;

    // ---- P0: stage G/Wc1/bc1 + per-row meta ----
    for (int i = t; i < N_NODES * D_INF; i += 1024) s_G[i] = G[i];
    for (int i = t; i < D_INF * H; i += 1024) s_Wc1[i] = Wc1[i];
    if (t < H) s_bc1[t] = bc1[t];
    if (t < 3) {
        int c = cnt[v0 + t];
        s_cc[t] = min(c, CAP);
        s_dv[t] = rsqrtf((float)(c + 1));
    }
    __syncthreads();
    if (q < 3) {
        int ccq = s_cc[q];
        for (int i = tc; i < ccq; i += 256) {
            int s = slots[(v0 + q) * CAP + i];
            s_s[q][i] = s;
            s_w[q][i] = rsqrtf((float)(cnt[s] + 1)) * s_dv[q];
        }
    }
    __syncthreads();

    // ---- P1: agg rows; h1 values rematerialized from G ----
    if (q < 3) {
        float dv = s_dv[q];
        // self-loop
        float a0 = s_bc1[tc];
        #pragma unroll
        for (int k = 0; k < D_INF; ++k)
            a0 = fmaf(s_G[(v0 + q) * D_INF + k], s_Wc1[k * H + tc], a0);
        float hv = (a0 > 0.f) ? a0 : expm1f(a0);
        float acc = dv * dv * hv;
        int ccq = s_cc[q];
        for (int n = 0; n < ccq; ++n) {
            int s = s_s[q][n];
            float a = s_bc1[tc];
            #pragma unroll
            for (int k = 0; k < D_INF; ++k)
                a = fmaf(s_G[s * D_INF + k], s_Wc1[k * H + tc], a);
            float h = (a > 0.f) ? a : expm1f(a);
            acc = fmaf(s_w[q][n], h, acc);
        }
        s_agg[q][tc] = acc;
    }
    __syncthreads();

    // ---- P2: h2 = agg @ Wc2 + bc2 ----
    {
        float a[3][16];
        #pragma unroll
        for (int r = 0; r < 3; ++r)
            #pragma unroll
            for (int qq = 0; qq < 4; ++qq) {
                float4 v = *(const float4*)&s_agg[r][k0 + qq * 4];
                a[r][qq * 4 + 0] = v.x; a[r][qq * 4 + 1] = v.y;
                a[r][qq * 4 + 2] = v.z; a[r][qq * 4 + 3] = v.w;
            }
        float4 c0 = {0.f, 0.f, 0.f, 0.f}, c1 = c0, c2 = c0;
        #pragma unroll
        for (int kk = 0; kk < 16; ++kk) {
            float4 wv = *(const float4*)(Wc2 + (size_t)(k0 + kk) * H + (lane << 2));
            c0.x = fmaf(a[0][kk], wv.x, c0.x); c0.y = fmaf(a[0][kk], wv.y, c0.y);
            c0.z = fmaf(a[0][kk], wv.z, c0.z); c0.w = fmaf(a[0][kk], wv.w, c0.w);
            c1.x = fmaf(a[1][kk], wv.x, c1.x); c1.y = fmaf(a[1][kk], wv.y, c1.y);
            c1.z = fmaf(a[1][kk], wv.z, c1.z); c1.w = fmaf(a[1][kk], wv.w, c1.w);
            c2.x = fmaf(a[2][kk], wv.x, c2.x); c2.y = fmaf(a[2][kk], wv.y, c2.y);
            c2.z = fmaf(a[2][kk], wv.z, c2.z); c2.w = fmaf(a[2][kk], wv.w, c2.w);
        }
        *(float4*)&s_part[w][0][lane << 2] = c0;
        *(float4*)&s_part[w][1][lane << 2] = c1;
        *(float4*)&s_part[w][2][lane << 2] = c2;
    }
    __syncthreads();
    if (t < 3 * H) {
        int r = t >> 8, c = t & 255;
        float v = bc2[c];
        #pragma unroll
        for (int ww = 0; ww < 16; ++ww) v += s_part[ww][r][c];
        s_h2[r][c] = v;
    }
    __syncthreads();

    // ---- P3: [ai | ajT] = h2 @ [We1a | We1b] (+be1 on j-half) ----
    {
        float a[3][16];
        #pragma unroll
        for (int r = 0; r < 3; ++r)
            #pragma unroll
            for (int qq = 0; qq < 4; ++qq) {
                float4 v = *(const float4*)&s_h2[r][k0 + qq * 4];
                a[r][qq * 4 + 0] = v.x; a[r][qq * 4 + 1] = v.y;
                a[r][qq * 4 + 2] = v.z; a[r][qq * 4 + 3] = v.w;
            }
        float4 ca0 = {0.f, 0.f, 0.f, 0.f}, ca1 = ca0, ca2 = ca0;
        float4 cb0 = ca0, cb1 = ca0, cb2 = ca0;
        #pragma unroll
        for (int kk = 0; kk < 16; ++kk) {
            int k = k0 + kk;
            float4 wa = *(const float4*)(We1 + (size_t)k * H + (lane << 2));
            float4 wb = *(const float4*)(We1 + (size_t)(H + k) * H + (lane << 2));
            ca0.x = fmaf(a[0][kk], wa.x, ca0.x); ca0.y = fmaf(a[0][kk], wa.y, ca0.y);
            ca0.z = fmaf(a[0][kk], wa.z, ca0.z); ca0.w = fmaf(a[0][kk], wa.w, ca0.w);
            ca1.x = fmaf(a[1][kk], wa.x, ca1.x); ca1.y = fmaf(a[1][kk], wa.y, ca1.y);
            ca1.z = fmaf(a[1][kk], wa.z, ca1.z); ca1.w = fmaf(a[1][kk], wa.w, ca1.w);
            ca2.x = fmaf(a[2][kk], wa.x, ca2.x); ca2.y = fmaf(a[2][kk], wa.y, ca2.y);
            ca2.z = fmaf(a[2][kk], wa.z, ca2.z); ca2.w = fmaf(a[2][kk], wa.w, ca2.w);
            cb0.x = fmaf(a[0][kk], wb.x, cb0.x); cb0.y = fmaf(a[0][kk], wb.y, cb0.y);
            cb0.z = fmaf(a[0][kk], wb.z, cb0.z); cb0.w = fmaf(a[0][kk], wb.w, cb0.w);
            cb1.x = fmaf(a[1][kk], wb.x, cb1.x); cb1.y = fmaf(a[1][kk], wb.y, cb1.y);
            cb1.z = fmaf(a[1][kk], wb.z, cb1.z); cb1.w = fmaf(a[1][kk], wb.w, cb1.w);
            cb2.x = fmaf(a[2][kk], wb.x, cb2.x); cb2.y = fmaf(a[2][kk], wb.y, cb2.y);
            cb2.z = fmaf(a[2][kk], wb.z, cb2.z); cb2.w = fmaf(a[2][kk], wb.w, cb2.w);
        }
        *(float4*)&s_part[w][0][lane << 2] = ca0;
        *(float4*)&s_part[w][1][lane << 2] = ca1;
        *(float4*)&s_part[w][2][lane << 2] = ca2;
        *(float4*)&s_part[w][3][lane << 2] = cb0;
        *(float4*)&s_part[w][4][lane << 2] = cb1;
        *(float4*)&s_part[w][5][lane << 2] = cb2;
    }
    __syncthreads();
    for (int idx = t; idx < 6 * H; idx += 1024) {
        int r6 = idx >> 8, c = idx & 255;
        float v = 0.f;
        #pragma unroll
        for (int ww = 0; ww < 16; ++ww) v += s_part[ww][r6][c];
        if (r6 < 3) aib[(size_t)(v0 + r6) * H + c] = v;
        else        ajcT[(size_t)c * N_NODES + v0 + (r6 - 3)] = v + be1[c];
    }
}

// ============ K3 k_pair2: logits + fused row softmax ============
// 512 thr = 8 waves x 32-h slices; j as 3 x float4 chunks; partials in LDS.
__global__ __launch_bounds__(512) void k_pair2(
    const float* __restrict__ aib, const float* __restrict__ ajcT,
    const float* __restrict__ We2, float* __restrict__ out) {
    __shared__ float s_ai[3 * H];
    __shared__ float s_w2[H];
    __shared__ __align__(16) float s_p[8 * 3 * N_NODES];   // 73.7 KB
    __shared__ float s_lg[3 * N_NODES];
    __shared__ float red[3 * 256];
    const int t = threadIdx.x, b = blockIdx.x;
    const int lane = t & 63, w = t >> 6;
    const int i0 = b * 3, h0 = w * 32;

    for (int i = t; i < 3 * H; i += 512)
        s_ai[i] = aib[(size_t)(i0 + (i >> 8)) * H + (i & 255)];
    if (t < H) s_w2[t] = We2[t];
    __syncthreads();

    float4 acc[3][3];
    #pragma unroll
    for (int r = 0; r < 3; ++r)
        #pragma unroll
        for (int jj = 0; jj < 3; ++jj)
            acc[r][jj] = make_float4(0.f, 0.f, 0.f, 0.f);

    #pragma unroll 4
    for (int hh = 0; hh < 32; ++hh) {
        int h = h0 + hh;
        float wv = s_w2[h];
        float a0 = s_ai[h], a1 = s_ai[H + h], a2 = s_ai[2 * H + h];
        const float* col = ajcT + (size_t)h * N_NODES + (lane << 2);
        #pragma unroll
        for (int jj = 0; jj < 3; ++jj) {
            float4 bv = *(const float4*)(col + jj * 256);
            acc[0][jj].x = fmaf(fmaxf(a0 + bv.x, 0.f), wv, acc[0][jj].x);
            acc[0][jj].y = fmaf(fmaxf(a0 + bv.y, 0.f), wv, acc[0][jj].y);
            acc[0][jj].z = fmaf(fmaxf(a0 + bv.z, 0.f), wv, acc[0][jj].z);
            acc[0][jj].w = fmaf(fmaxf(a0 + bv.w, 0.f), wv, acc[0][jj].w);
            acc[1][jj].x = fmaf(fmaxf(a1 + bv.x, 0.f), wv, acc[1][jj].x);
            acc[1][jj].y = fmaf(fmaxf(a1 + bv.y, 0.f), wv, acc[1][jj].y);
            acc[1][jj].z = fmaf(fmaxf(a1 + bv.z, 0.f), wv, acc[1][jj].z);
            acc[1][jj].w = fmaf(fmaxf(a1 + bv.w, 0.f), wv, acc[1][jj].w);
            acc[2][jj].x = fmaf(fmaxf(a2 + bv.x, 0.f), wv, acc[2][jj].x);
            acc[2][jj].y = fmaf(fmaxf(a2 + bv.y, 0.f), wv, acc[2][jj].y);
            acc[2][jj].z = fmaf(fmaxf(a2 + bv.z, 0.f), wv, acc[2][jj].z);
            acc[2][jj].w = fmaf(fmaxf(a2 + bv.w, 0.f), wv, acc[2][jj].w);
        }
    }
    #pragma unroll
    for (int r = 0; r < 3; ++r)
        #pragma unroll
        for (int jj = 0; jj < 3; ++jj)
            *(float4*)&s_p[(w * 3 + r) * N_NODES + jj * 256 + (lane << 2)] = acc[r][jj];
    __syncthreads();

    for (int idx = t; idx < 3 * N_NODES; idx += 512) {
        int r = idx / N_NODES, j = idx - r * N_NODES;
        float v = 0.f;
        #pragma unroll
        for (int ww = 0; ww < 8; ++ww) v += s_p[(ww * 3 + r) * N_NODES + j];
        s_lg[idx] = (j == i0 + r) ? -INFINITY : v;
    }
    __syncthreads();

    const int tc = t & 255, th = t >> 8;
    if (th == 0) {
        red[tc] = fmaxf(fmaxf(s_lg[tc], s_lg[tc + 256]), s_lg[tc + 512]);
        red[512 + tc] = fmaxf(fmaxf(s_lg[1536 + tc], s_lg[1536 + tc + 256]),
                              s_lg[1536 + tc + 512]);
    } else {
        red[256 + tc] = fmaxf(fmaxf(s_lg[768 + tc], s_lg[768 + tc + 256]),
                              s_lg[768 + tc + 512]);
    }
    __syncthreads();
    for (int s = 128; s > 0; s >>= 1) {
        if (th == 0 && tc < s) {
            red[tc] = fmaxf(red[tc], red[tc + s]);
            red[512 + tc] = fmaxf(red[512 + tc], red[512 + tc + s]);
        } else if (th == 1 && tc < s) {
            red[256 + tc] = fmaxf(red[256 + tc], red[256 + tc + s]);
        }
        __syncthreads();
    }
    float mx0 = red[0], mx1 = red[256], mx2 = red[512];
    __syncthreads();
    if (th == 0) {
        red[tc] = __expf(s_lg[tc] - mx0) + __expf(s_lg[tc + 256] - mx0)
                + __expf(s_lg[tc + 512] - mx0);
        red[512 + tc] = __expf(s_lg[1536 + tc] - mx2) + __expf(s_lg[1536 + tc + 256] - mx2)
                      + __expf(s_lg[1536 + tc + 512] - mx2);
    } else {
        red[256 + tc] = __expf(s_lg[768 + tc] - mx1) + __expf(s_lg[768 + tc + 256] - mx1)
                      + __expf(s_lg[768 + tc + 512] - mx1);
    }
    __syncthreads();
    for (int s = 128; s > 0; s >>= 1) {
        if (th == 0 && tc < s) {
            red[tc] += red[tc + s];
            red[512 + tc] += red[512 + tc + s];
        } else if (th == 1 && tc < s) {
            red[256 + tc] += red[256 + tc + s];
        }
        __syncthreads();
    }
    float iv0 = 1.0f / red[0], iv1 = 1.0f / red[256], iv2 = 1.0f / red[512];

    for (int idx = t; idx < 3 * N_NODES; idx += 512) {
        int r = idx / N_NODES, j = idx - r * N_NODES;
        float m = (r == 0) ? mx0 : (r == 1) ? mx1 : mx2;
        float iv = (r == 0) ? iv0 : (r == 1) ? iv1 : iv2;
        out[(size_t)(i0 + r) * N_NODES + j] = __expf(s_lg[idx] - m) * iv;
    }
}

extern "C" void kernel_launch(void* const* d_in, const int* in_sizes, int n_in,
                              void* d_out, int out_size, void* d_ws, size_t ws_size,
                              hipStream_t stream) {
    const float* x   = (const float*)d_in[0];
    const int*   ei  = (const int*)d_in[1];
    const float* Wc1 = (const float*)d_in[2];
    const float* bc1 = (const float*)d_in[3];
    const float* Wc2 = (const float*)d_in[4];
    const float* bc2 = (const float*)d_in[5];
    const float* We1 = (const float*)d_in[6];
    const float* be1 = (const float*)d_in[7];
    const float* We2 = (const float*)d_in[8];
    // be2 (d_in[9]) unused: softmax shift-invariant (TEMPERATURE=1 likewise).
    float* out = (float*)d_out;

    char* ws = (char*)d_ws;
    int*   cnt   = (int*)(ws + 0);            // 3072
    int*   slots = (int*)(ws + 4096);         // 393216
    float* G     = (float*)(ws + 397312);     // 18432
    float* aib   = (float*)(ws + 417792);     // 786432
    float* ajcT  = (float*)(ws + 1204224);    // 786432

    k_prep<<<N_NODES / 3, 256, 0, stream>>>(x, ei, cnt, slots, G);
    k_mid<<<N_NODES / 3, 1024, 0, stream>>>(G, cnt, slots, Wc1, bc1, Wc2, bc2,
                                            We1, be1, aib, ajcT);
    k_pair2<<<N_NODES / 3, 512, 0, stream>>>(aib, ajcT, We2, out);
}

// Round 15
// 53.202 us; speedup vs baseline: 1.2780x; 1.0173x over previous
//
#include <hip/hip_runtime.h>
#include <math.h>

#define N_NODES 768
#define N_EDGES 12288
#define D_INF 6
#define H 256
#define CAP 128
#define LC 256

// ============ K1 k_prep: LDS histogram + compact -> cnt/slots + h1 (3 nodes) ======
__global__ __launch_bounds__(256) void k_prep(
    const float* __restrict__ x, const int* __restrict__ ei,
    const float* __restrict__ Wc1, const float* __restrict__ bc1,
    int* __restrict__ cnt_g, int* __restrict__ slots, float* __restrict__ h1) {
    __shared__ int s_cnt[N_NODES];
    __shared__ int s_list[LC];
    __shared__ int s_nm, s_pos[3];
    __shared__ float s_agg[3][D_INF];
    const int t = threadIdx.x, b = blockIdx.x, v0 = b * 3;
    const int* src = ei;
    const int* dst = ei + N_EDGES;

    for (int v = t; v < N_NODES; v += 256) s_cnt[v] = 0;
    if (t == 0) s_nm = 0;
    if (t < 3) s_pos[t] = 0;
    if (t < 3 * D_INF) ((float*)s_agg)[t] = 0.f;
    __syncthreads();
    for (int e = t; e < N_EDGES; e += 256) {
        int d = dst[e];
        atomicAdd(&s_cnt[d], 1);
        unsigned li = (unsigned)(d - v0);
        if (li < 3u) {
            int p = atomicAdd(&s_nm, 1);
            if (p < LC) s_list[p] = (src[e] << 2) | (int)li;
        }
    }
    __syncthreads();
    const int nm = min(s_nm, LC);
    if (t < 3) cnt_g[v0 + t] = s_cnt[v0 + t];
    for (int m = t; m < nm; m += 256) {
        int pk = s_list[m];
        int s = pk >> 2, li = pk & 3;
        int p = atomicAdd(&s_pos[li], 1);
        if (p < CAP) slots[(v0 + li) * CAP + p] = s;
        float w = rsqrtf((float)(s_cnt[s] + 1)) * rsqrtf((float)(s_cnt[v0 + li] + 1));
        #pragma unroll
        for (int k = 0; k < D_INF; ++k)
            atomicAdd(&s_agg[li][k], w * x[s * D_INF + k]);
    }
    if (t < 3) {   // self-loops
        int v = v0 + t;
        float dv2 = 1.0f / (float)(s_cnt[v] + 1);
        #pragma unroll
        for (int k = 0; k < D_INF; ++k)
            atomicAdd(&s_agg[t][k], dv2 * x[v * D_INF + k]);
    }
    __syncthreads();
    #pragma unroll
    for (int r = 0; r < 3; ++r) {
        float acc = bc1[t];
        #pragma unroll
        for (int k = 0; k < D_INF; ++k)
            acc = fmaf(s_agg[r][k], Wc1[k * H + t], acc);
        h1[(v0 + r) * H + t] = (acc > 0.f) ? acc : expm1f(acc);
    }
}

// ============ K2 k_mid: agg(h1) -> h2 -> ai/ajcT, all row-local, 3 nodes/block ======
// 1024 thr. P1: gather (768 thr, preloaded (s,w)). P2: h2 = agg@Wc2+bc2
// (16-wave k-split, A from LDS broadcast, W streamed global b128).
// P3: [ai|ajT] = h2@We1 (+be1 on j-half), same structure, 6 outputs.
__global__ __launch_bounds__(1024) void k_mid(
    const float* __restrict__ h1, const int* __restrict__ cnt,
    const int* __restrict__ slots, const float* __restrict__ Wc2,
    const float* __restrict__ bc2, const float* __restrict__ We1,
    const float* __restrict__ be1, float* __restrict__ aib,
    float* __restrict__ ajcT) {
    __shared__ int   s_s[3][CAP];
    __shared__ float s_w[3][CAP];
    __shared__ int   s_cc[3];
    __shared__ float s_dv[3];
    __shared__ __align__(16) float s_agg[3][H];
    __shared__ __align__(16) float s_h2[3][H];
    __shared__ __align__(16) float s_part[16][6][H];   // 98.3 KB (P2 uses [..][0..2][..])
    const int t = threadIdx.x, b = blockIdx.x;
    const int q = t >> 8, tc = t & 255;
    const int lane = t & 63, w = t >> 6;
    const int v0 = b * 3, k0 = w * 16;

    // ---- P0: (s,w) preload, independent parallel loads ----
    if (t < 3) {
        int c = cnt[v0 + t];
        s_cc[t] = min(c, CAP);
        s_dv[t] = rsqrtf((float)(c + 1));
    }
    __syncthreads();
    if (q < 3) {
        int ccq = s_cc[q];
        for (int i = tc; i < ccq; i += 256) {
            int s = slots[(v0 + q) * CAP + i];
            s_s[q][i] = s;
            s_w[q][i] = rsqrtf((float)(cnt[s] + 1)) * s_dv[q];
        }
    }
    __syncthreads();

    // ---- P1: agg = (A h1) rows ----
    if (q < 3) {
        float dv = s_dv[q];
        float acc = dv * dv * h1[(size_t)(v0 + q) * H + tc];
        int ccq = s_cc[q];
        #pragma unroll 4
        for (int n = 0; n < ccq; ++n)
            acc = fmaf(s_w[q][n], h1[(size_t)s_s[q][n] * H + tc], acc);
        s_agg[q][tc] = acc;
    }
    __syncthreads();

    // ---- P2: h2 = agg @ Wc2 + bc2 ----
    {
        float a[3][16];
        #pragma unroll
        for (int r = 0; r < 3; ++r)
            #pragma unroll
            for (int qq = 0; qq < 4; ++qq) {
                float4 v = *(const float4*)&s_agg[r][k0 + qq * 4];
                a[r][qq * 4 + 0] = v.x; a[r][qq * 4 + 1] = v.y;
                a[r][qq * 4 + 2] = v.z; a[r][qq * 4 + 3] = v.w;
            }
        float4 c0 = {0.f, 0.f, 0.f, 0.f}, c1 = c0, c2 = c0;
        #pragma unroll
        for (int kk = 0; kk < 16; ++kk) {
            float4 wv = *(const float4*)(Wc2 + (size_t)(k0 + kk) * H + (lane << 2));
            c0.x = fmaf(a[0][kk], wv.x, c0.x); c0.y = fmaf(a[0][kk], wv.y, c0.y);
            c0.z = fmaf(a[0][kk], wv.z, c0.z); c0.w = fmaf(a[0][kk], wv.w, c0.w);
            c1.x = fmaf(a[1][kk], wv.x, c1.x); c1.y = fmaf(a[1][kk], wv.y, c1.y);
            c1.z = fmaf(a[1][kk], wv.z, c1.z); c1.w = fmaf(a[1][kk], wv.w, c1.w);
            c2.x = fmaf(a[2][kk], wv.x, c2.x); c2.y = fmaf(a[2][kk], wv.y, c2.y);
            c2.z = fmaf(a[2][kk], wv.z, c2.z); c2.w = fmaf(a[2][kk], wv.w, c2.w);
        }
        *(float4*)&s_part[w][0][lane << 2] = c0;
        *(float4*)&s_part[w][1][lane << 2] = c1;
        *(float4*)&s_part[w][2][lane << 2] = c2;
    }
    __syncthreads();
    if (t < 3 * H) {
        int r = t >> 8, c = t & 255;
        float v = bc2[c];
        #pragma unroll
        for (int ww = 0; ww < 16; ++ww) v += s_part[ww][r][c];
        s_h2[r][c] = v;
    }
    __syncthreads();

    // ---- P3: [ai | ajT] = h2 @ [We1a | We1b] (+be1 on j-half) ----
    {
        float a[3][16];
        #pragma unroll
        for (int r = 0; r < 3; ++r)
            #pragma unroll
            for (int qq = 0; qq < 4; ++qq) {
                float4 v = *(const float4*)&s_h2[r][k0 + qq * 4];
                a[r][qq * 4 + 0] = v.x; a[r][qq * 4 + 1] = v.y;
                a[r][qq * 4 + 2] = v.z; a[r][qq * 4 + 3] = v.w;
            }
        float4 ca0 = {0.f, 0.f, 0.f, 0.f}, ca1 = ca0, ca2 = ca0;
        float4 cb0 = ca0, cb1 = ca0, cb2 = ca0;
        #pragma unroll
        for (int kk = 0; kk < 16; ++kk) {
            int k = k0 + kk;
            float4 wa = *(const float4*)(We1 + (size_t)k * H + (lane << 2));
            float4 wb = *(const float4*)(We1 + (size_t)(H + k) * H + (lane << 2));
            ca0.x = fmaf(a[0][kk], wa.x, ca0.x); ca0.y = fmaf(a[0][kk], wa.y, ca0.y);
            ca0.z = fmaf(a[0][kk], wa.z, ca0.z); ca0.w = fmaf(a[0][kk], wa.w, ca0.w);
            ca1.x = fmaf(a[1][kk], wa.x, ca1.x); ca1.y = fmaf(a[1][kk], wa.y, ca1.y);
            ca1.z = fmaf(a[1][kk], wa.z, ca1.z); ca1.w = fmaf(a[1][kk], wa.w, ca1.w);
            ca2.x = fmaf(a[2][kk], wa.x, ca2.x); ca2.y = fmaf(a[2][kk], wa.y, ca2.y);
            ca2.z = fmaf(a[2][kk], wa.z, ca2.z); ca2.w = fmaf(a[2][kk], wa.w, ca2.w);
            cb0.x = fmaf(a[0][kk], wb.x, cb0.x); cb0.y = fmaf(a[0][kk], wb.y, cb0.y);
            cb0.z = fmaf(a[0][kk], wb.z, cb0.z); cb0.w = fmaf(a[0][kk], wb.w, cb0.w);
            cb1.x = fmaf(a[1][kk], wb.x, cb1.x); cb1.y = fmaf(a[1][kk], wb.y, cb1.y);
            cb1.z = fmaf(a[1][kk], wb.z, cb1.z); cb1.w = fmaf(a[1][kk], wb.w, cb1.w);
            cb2.x = fmaf(a[2][kk], wb.x, cb2.x); cb2.y = fmaf(a[2][kk], wb.y, cb2.y);
            cb2.z = fmaf(a[2][kk], wb.z, cb2.z); cb2.w = fmaf(a[2][kk], wb.w, cb2.w);
        }
        *(float4*)&s_part[w][0][lane << 2] = ca0;
        *(float4*)&s_part[w][1][lane << 2] = ca1;
        *(float4*)&s_part[w][2][lane << 2] = ca2;
        *(float4*)&s_part[w][3][lane << 2] = cb0;
        *(float4*)&s_part[w][4][lane << 2] = cb1;
        *(float4*)&s_part[w][5][lane << 2] = cb2;
    }
    __syncthreads();
    for (int idx = t; idx < 6 * H; idx += 1024) {
        int r6 = idx >> 8, c = idx & 255;
        float v = 0.f;
        #pragma unroll
        for (int ww = 0; ww < 16; ++ww) v += s_part[ww][r6][c];
        if (r6 < 3) aib[(size_t)(v0 + r6) * H + c] = v;
        else        ajcT[(size_t)c * N_NODES + v0 + (r6 - 3)] = v + be1[c];
    }
}

// ============ K3 k_pair2: logits + fused row softmax ============
// 512 thr = 8 waves x 32-h slices; j as 3 x float4 chunks; partials in LDS.
__global__ __launch_bounds__(512) void k_pair2(
    const float* __restrict__ aib, const float* __restrict__ ajcT,
    const float* __restrict__ We2, float* __restrict__ out) {
    __shared__ float s_ai[3 * H];
    __shared__ float s_w2[H];
    __shared__ __align__(16) float s_p[8 * 3 * N_NODES];   // 73.7 KB
    __shared__ float s_lg[3 * N_NODES];
    __shared__ float red[3 * 256];
    const int t = threadIdx.x, b = blockIdx.x;
    const int lane = t & 63, w = t >> 6;
    const int i0 = b * 3, h0 = w * 32;

    for (int i = t; i < 3 * H; i += 512)
        s_ai[i] = aib[(size_t)(i0 + (i >> 8)) * H + (i & 255)];
    if (t < H) s_w2[t] = We2[t];
    __syncthreads();

    float4 acc[3][3];
    #pragma unroll
    for (int r = 0; r < 3; ++r)
        #pragma unroll
        for (int jj = 0; jj < 3; ++jj)
            acc[r][jj] = make_float4(0.f, 0.f, 0.f, 0.f);

    #pragma unroll 4
    for (int hh = 0; hh < 32; ++hh) {
        int h = h0 + hh;
        float wv = s_w2[h];
        float a0 = s_ai[h], a1 = s_ai[H + h], a2 = s_ai[2 * H + h];
        const float* col = ajcT + (size_t)h * N_NODES + (lane << 2);
        #pragma unroll
        for (int jj = 0; jj < 3; ++jj) {
            float4 bv = *(const float4*)(col + jj * 256);
            acc[0][jj].x = fmaf(fmaxf(a0 + bv.x, 0.f), wv, acc[0][jj].x);
            acc[0][jj].y = fmaf(fmaxf(a0 + bv.y, 0.f), wv, acc[0][jj].y);
            acc[0][jj].z = fmaf(fmaxf(a0 + bv.z, 0.f), wv, acc[0][jj].z);
            acc[0][jj].w = fmaf(fmaxf(a0 + bv.w, 0.f), wv, acc[0][jj].w);
            acc[1][jj].x = fmaf(fmaxf(a1 + bv.x, 0.f), wv, acc[1][jj].x);
            acc[1][jj].y = fmaf(fmaxf(a1 + bv.y, 0.f), wv, acc[1][jj].y);
            acc[1][jj].z = fmaf(fmaxf(a1 + bv.z, 0.f), wv, acc[1][jj].z);
            acc[1][jj].w = fmaf(fmaxf(a1 + bv.w, 0.f), wv, acc[1][jj].w);
            acc[2][jj].x = fmaf(fmaxf(a2 + bv.x, 0.f), wv, acc[2][jj].x);
            acc[2][jj].y = fmaf(fmaxf(a2 + bv.y, 0.f), wv, acc[2][jj].y);
            acc[2][jj].z = fmaf(fmaxf(a2 + bv.z, 0.f), wv, acc[2][jj].z);
            acc[2][jj].w = fmaf(fmaxf(a2 + bv.w, 0.f), wv, acc[2][jj].w);
        }
    }
    #pragma unroll
    for (int r = 0; r < 3; ++r)
        #pragma unroll
        for (int jj = 0; jj < 3; ++jj)
            *(float4*)&s_p[(w * 3 + r) * N_NODES + jj * 256 + (lane << 2)] = acc[r][jj];
    __syncthreads();

    for (int idx = t; idx < 3 * N_NODES; idx += 512) {
        int r = idx / N_NODES, j = idx - r * N_NODES;
        float v = 0.f;
        #pragma unroll
        for (int ww = 0; ww < 8; ++ww) v += s_p[(ww * 3 + r) * N_NODES + j];
        s_lg[idx] = (j == i0 + r) ? -INFINITY : v;
    }
    __syncthreads();

    const int tc = t & 255, th = t >> 8;
    if (th == 0) {
        red[tc] = fmaxf(fmaxf(s_lg[tc], s_lg[tc + 256]), s_lg[tc + 512]);
        red[512 + tc] = fmaxf(fmaxf(s_lg[1536 + tc], s_lg[1536 + tc + 256]),
                              s_lg[1536 + tc + 512]);
    } else {
        red[256 + tc] = fmaxf(fmaxf(s_lg[768 + tc], s_lg[768 + tc + 256]),
                              s_lg[768 + tc + 512]);
    }
    __syncthreads();
    for (int s = 128; s > 0; s >>= 1) {
        if (th == 0 && tc < s) {
            red[tc] = fmaxf(red[tc], red[tc + s]);
            red[512 + tc] = fmaxf(red[512 + tc], red[512 + tc + s]);
        } else if (th == 1 && tc < s) {
            red[256 + tc] = fmaxf(red[256 + tc], red[256 + tc + s]);
        }
        __syncthreads();
    }
    float mx0 = red[0], mx1 = red[256], mx2 = red[512];
    __syncthreads();
    if (th == 0) {
        red[tc] = __expf(s_lg[tc] - mx0) + __expf(s_lg[tc + 256] - mx0)
                + __expf(s_lg[tc + 512] - mx0);
        red[512 + tc] = __expf(s_lg[1536 + tc] - mx2) + __expf(s_lg[1536 + tc + 256] - mx2)
                      + __expf(s_lg[1536 + tc + 512] - mx2);
    } else {
        red[256 + tc] = __expf(s_lg[768 + tc] - mx1) + __expf(s_lg[768 + tc + 256] - mx1)
                      + __expf(s_lg[768 + tc + 512] - mx1);
    }
    __syncthreads();
    for (int s = 128; s > 0; s >>= 1) {
        if (th == 0 && tc < s) {
            red[tc] += red[tc + s];
            red[512 + tc] += red[512 + tc + s];
        } else if (th == 1 && tc < s) {
            red[256 + tc] += red[256 + tc + s];
        }
        __syncthreads();
    }
    float iv0 = 1.0f / red[0], iv1 = 1.0f / red[256], iv2 = 1.0f / red[512];

    for (int idx = t; idx < 3 * N_NODES; idx += 512) {
        int r = idx / N_NODES, j = idx - r * N_NODES;
        float m = (r == 0) ? mx0 : (r == 1) ? mx1 : mx2;
        float iv = (r == 0) ? iv0 : (r == 1) ? iv1 : iv2;
        out[(size_t)(i0 + r) * N_NODES + j] = __expf(s_lg[idx] - m) * iv;
    }
}

extern "C" void kernel_launch(void* const* d_in, const int* in_sizes, int n_in,
                              void* d_out, int out_size, void* d_ws, size_t ws_size,
                              hipStream_t stream) {
    const float* x   = (const float*)d_in[0];
    const int*   ei  = (const int*)d_in[1];
    const float* Wc1 = (const float*)d_in[2];
    const float* bc1 = (const float*)d_in[3];
    const float* Wc2 = (const float*)d_in[4];
    const float* bc2 = (const float*)d_in[5];
    const float* We1 = (const float*)d_in[6];
    const float* be1 = (const float*)d_in[7];
    const float* We2 = (const float*)d_in[8];
    // be2 (d_in[9]) unused: softmax shift-invariant (TEMPERATURE=1 likewise).
    float* out = (float*)d_out;

    char* ws = (char*)d_ws;
    int*   cnt  = (int*)(ws + 0);            // 3072
    int*   slots= (int*)(ws + 4096);         // 393216
    float* h1   = (float*)(ws + 397312);     // 786432
    float* aib  = (float*)(ws + 1183744);    // 786432
    float* ajcT = (float*)(ws + 1970176);    // 786432

    k_prep<<<N_NODES / 3, 256, 0, stream>>>(x, ei, Wc1, bc1, cnt, slots, h1);
    k_mid<<<N_NODES / 3, 1024, 0, stream>>>(h1, cnt, slots, Wc2, bc2, We1, be1,
                                            aib, ajcT);
    k_pair2<<<N_NODES / 3, 512, 0, stream>>>(aib, ajcT, We2, out);
}